// Round 2
// baseline (6317.583 us; speedup 1.0000x reference)
//
#include <hip/hip_runtime.h>

// ---------------------------------------------------------------------------
// GenesisV1: embed -> 256-step gated node recurrence -> LN -> vocab logits
//
// combined@W = x_t@W_top (precomputed batched GEMM) + nodes@W_bot (recurrent).
// Recurrence: grid 32 m-blocks x 8 n-slices = 256 WGs (1/CU). Each wave keeps
// its 2 weight n-tiles (gate+cand) fully in VGPRs (128 regs); per step the 8
// WGs of an m-block all-gather h via global double-buffer + release/acquire
// flags (agent scope). Groups are independent -> no deadlock risk.
// Fragment layouts (mfma_f32_16x16x32_bf16):
//   A-frag: lane l holds A[m = l&15][k = (l>>4)*8 + j], j=0..7   (16B/lane)
//   B-frag: lane l holds B[k = (l>>4)*8 + j][n = l&15]
//   D:      lane l holds D[row = (l>>4)*4 + r][col = l&15]
// ---------------------------------------------------------------------------

#define NBATCH 8
#define SEQ    256
#define DM     512
#define VOCAB  32000
#define KT     16     // DM/32 k-tiles

typedef __attribute__((ext_vector_type(8))) short s8v;  // 8 bf16 in 4 VGPRs
typedef __attribute__((ext_vector_type(4))) float f4v;

// ---- workspace layout (bytes) ----
#define OFF_XFRAG  0u          // [128 mt][16 kt][64][8] bf16 : 2 MB (dead after k_xgemm)
#define OFF_HBUF   0u          // reuse xfrag region: [2][32 g][16 m][512 k] bf16 = 1 MB
#define OFF_BPKTOP 2097152u    // [64 nt][16 kt][64][8] bf16 : 1 MB
#define OFF_BPKREC 3145728u    // same                       : 1 MB
#define OFF_WHPK   4194304u    // [2000 nt][16][64][8] bf16  : 32.77 MB
#define OFF_XGU    36962304u   // [2048][1024] f32           : 8 MB
#define OFF_PART   45350912u   // [8][4][256][512] f32       : 16.78 MB
#define OFF_NORM   62128128u   // [128 mt][16][64][8] bf16   : 2 MB
#define OFF_FLAGS  64225280u   // [32 g][32] int             : 4 KB (poison 0xAA = negative = not-ready)

__device__ __forceinline__ short f2bf(float f) {
  unsigned u = __builtin_bit_cast(unsigned, f);
  u += 0x7fffu + ((u >> 16) & 1u);          // round-to-nearest-even
  return (short)(u >> 16);
}
__device__ __forceinline__ float fsig(float x) {
  float e = __builtin_amdgcn_exp2f(-1.4426950408889634f * x);
  return __builtin_amdgcn_rcpf(1.0f + e);
}
__device__ __forceinline__ float ftanh(float x) {
  float xc = fminf(fmaxf(x, -15.0f), 15.0f); // avoid inf/inf -> NaN
  float e = __builtin_amdgcn_exp2f(2.8853900817779268f * xc); // e^(2x)
  return (e - 1.0f) * __builtin_amdgcn_rcpf(e + 1.0f);
}
__device__ __forceinline__ void gload_lds16(const void* g, void* l) {
  __builtin_amdgcn_global_load_lds(
      (const __attribute__((address_space(1))) unsigned int*)g,
      (__attribute__((address_space(3))) unsigned int*)l, 16, 0, 0);
}

// ---- pack Wg/Wu (both [1024,512] f32) into top (x-part) and bottom (node-
// part) B-fragment tensors. nt 0..31 = gate cols, nt 32..63 = cand cols. ----
__global__ __launch_bounds__(256) void k_packw(const float* __restrict__ Wg,
                                               const float* __restrict__ Wu,
                                               short* __restrict__ top,
                                               short* __restrict__ rec) {
  int t = blockIdx.x * 256 + threadIdx.x;   // 131072 total
  int l = t & 63, kt = (t >> 6) & 15, nt = (t >> 10) & 31;
  int ub = (t >> 15) & 1, tb = (t >> 16) & 1;
  const float* src = ub ? Wu : Wg;
  int row0 = tb * 512 + kt * 32 + ((l >> 4) << 3);
  int col  = nt * 16 + (l & 15);
  short* dst = tb ? rec : top;
  int base = (((ub * 32 + nt) * KT + kt) * 64 + l) * 8;
#pragma unroll
  for (int j = 0; j < 8; ++j) dst[base + j] = f2bf(src[(row0 + j) * 512 + col]);
}

// ---- pack Wh [512,32000] f32 -> bf16 B-fragments ----
__global__ __launch_bounds__(256) void k_packwh(const float* __restrict__ Wh,
                                                short* __restrict__ whpk) {
  int t = blockIdx.x * 256 + threadIdx.x;   // 2,048,000 total
  int l = t & 63, kt = (t >> 6) & 15, nt = t >> 10;  // nt 0..1999
  int row0 = kt * 32 + ((l >> 4) << 3);
  int col  = nt * 16 + (l & 15);
  int base = ((nt * KT + kt) * 64 + l) * 8;
#pragma unroll
  for (int j = 0; j < 8; ++j) whpk[base + j] = f2bf(Wh[(row0 + j) * VOCAB + col]);
}

// ---- gather x = embedding[idx] -> bf16 A-fragments ----
__global__ __launch_bounds__(256) void k_gather(const int* __restrict__ idx,
                                                const float* __restrict__ emb,
                                                short* __restrict__ xfrag) {
  int t = blockIdx.x * 256 + threadIdx.x;   // 131072 total
  int l = t & 63, kt = (t >> 6) & 15, mt = t >> 10;  // mt 0..127
  int m = mt * 16 + (l & 15);
  int tok = idx[m];
  const float* e = emb + (long)tok * DM + kt * 32 + ((l >> 4) << 3);
  int base = ((mt * KT + kt) * 64 + l) * 8;
#pragma unroll
  for (int j = 0; j < 8; ++j) xfrag[base + j] = f2bf(e[j]);
}

// ---- Xgu = x @ [Wg_top|Wu_top] + [bg|bu] : [2048][1024] f32 ----
// NOTE: xfrag shares ws with hbuf, but k_recur only reads hbuf slots it wrote.
__global__ __launch_bounds__(256) void k_xgemm(const short* __restrict__ xfrag,
                                               const short* __restrict__ bpk,
                                               const float* __restrict__ bg,
                                               const float* __restrict__ bu,
                                               float* __restrict__ xgu) {
  int tid = threadIdx.x, l = tid & 63, w = tid >> 6;
  int mtb = blockIdx.x;            // 0..31 (4 mt each)
  int nt  = blockIdx.y * 4 + w;    // 0..63
  f4v acc[4];
#pragma unroll
  for (int mi = 0; mi < 4; ++mi) acc[mi] = 0;
  for (int kt = 0; kt < KT; ++kt) {
    s8v bf = *(const s8v*)(bpk + ((nt * KT + kt) * 64 + l) * 8);
#pragma unroll
    for (int mi = 0; mi < 4; ++mi) {
      s8v a = *(const s8v*)(xfrag + (((mtb * 4 + mi) * KT + kt) * 64 + l) * 8);
      acc[mi] = __builtin_amdgcn_mfma_f32_16x16x32_bf16(a, bf, acc[mi], 0, 0, 0);
    }
  }
  int n = nt * 16 + (l & 15);
  float bias = (n < 512) ? bg[n] : bu[n - 512];
#pragma unroll
  for (int mi = 0; mi < 4; ++mi)
#pragma unroll
    for (int r = 0; r < 4; ++r) {
      int m = (mtb * 4 + mi) * 16 + ((l >> 4) << 2) + r;
      xgu[m * 1024 + n] = acc[mi][r] + bias;
    }
}

// ---- the recurrence: 256 WGs x 256 threads.
// blockIdx = g + 32*s : g = group (bat*4+nodeblock), s = n-slice 0..7.
// Wave w of slice s owns h-cols [64s+16w, 64s+16w+16): gate nt 4s+w,
// cand nt 32+4s+w, both held in VGPRs. Per step: spin on group flags,
// acquire, gather h(t) A-frags into LDS (global_load_lds), 32 MFMAs,
// gate/cand/update, write h(t+1) slice + release flag.
__global__ __launch_bounds__(256, 1) void k_recur(const short* __restrict__ bpk,
                                                  const float* __restrict__ xgu,
                                                  const float* __restrict__ mn,
                                                  float* __restrict__ part,
                                                  short* __restrict__ hbuf,
                                                  int* __restrict__ flags) {
  __shared__ short hlds[2][KT][64][8];      // 2 x 16 KB A-frag staging
  const int tid = threadIdx.x;
  const int l = tid & 63, w = tid >> 6;     // wave 0..3
  const int lm = l & 15, lq = l >> 4;
  const int s = blockIdx.x >> 5;            // n-slice (member) 0..7
  const int g = blockIdx.x & 31;            // group: same XCD for all members
  const int bat = g >> 2, nb = g & 3;
  const int col = 64 * s + 16 * w + lm;     // this thread's h column

  // weight fragments -> VGPRs (128 regs): gate nt 4s+w, cand nt 32+4s+w
  s8v wgt_g[KT], wgt_u[KT];
  {
    const int ntg = 4 * s + w, ntu = 32 + 4 * s + w;
#pragma unroll
    for (int kt = 0; kt < KT; ++kt) {
      wgt_g[kt] = *(const s8v*)(bpk + ((ntg * KT + kt) * 64 + l) * 8);
      wgt_u[kt] = *(const s8v*)(bpk + ((ntu * KT + kt) * 64 + l) * 8);
    }
  }
  // h master (4 rows per thread) + h(0) A-frags from manifold_nodes
  float hm[4];
#pragma unroll
  for (int r = 0; r < 4; ++r) hm[r] = mn[(nb * 16 + lq * 4 + r) * DM + col];
#pragma unroll
  for (int j = 0; j < 4; ++j) {
    int kt = 4 * w + j;
    const float* src = mn + (nb * 16 + lm) * DM + kt * 32 + lq * 8;
    s8v v;
#pragma unroll
    for (int e = 0; e < 8; ++e) v[e] = f2bf(src[e]);
    *(s8v*)(&hlds[0][kt][l][0]) = v;
  }

  const int fbase = g * 32;
  for (int t = 0; t < SEQ; ++t) {
    // prefetch per-timestep x-part preactivations (independent of flags)
    const float* xrow = xgu + (bat * SEQ + t) * 1024;
    float xg = xrow[col], xu = xrow[512 + col];
    if (t > 0) {
      // spin until all 32 wave-flags of the group reach t (h(t) published)
      const int fidx = fbase + (l & 31);
      int guard = 0;
      while (true) {
        int v = __hip_atomic_load(flags + fidx, __ATOMIC_RELAXED,
                                  __HIP_MEMORY_SCOPE_AGENT);
        if (__ballot(v >= t) == ~0ull) break;
        if (++guard > (1 << 22)) break;     // bail -> wrong answer, not hang
        __builtin_amdgcn_s_sleep(2);
      }
      __builtin_amdgcn_fence(__ATOMIC_ACQUIRE, "agent");
      // gather h(t) -> LDS A-frags (wave w fills kt 4w..4w+3)
      const short* hsrc = hbuf + ((t & 1) * 32 + g) * (16 * DM);
#pragma unroll
      for (int j = 0; j < 4; ++j) {
        int kt = 4 * w + j;
        gload_lds16(hsrc + lm * DM + kt * 32 + lq * 8, &hlds[t & 1][kt][0][0]);
      }
    }
    __syncthreads();                         // also drains global_load_lds
    const int buf = t & 1;
    f4v accg = {0.f, 0.f, 0.f, 0.f}, accu = {0.f, 0.f, 0.f, 0.f};
#pragma unroll
    for (int kt = 0; kt < KT; ++kt) {
      s8v a = *(const s8v*)(&hlds[buf][kt][l][0]);
      accg = __builtin_amdgcn_mfma_f32_16x16x32_bf16(a, wgt_g[kt], accg, 0, 0, 0);
      accu = __builtin_amdgcn_mfma_f32_16x16x32_bf16(a, wgt_u[kt], accu, 0, 0, 0);
    }
    // epilogue: gate/cand/update, publish h(t+1) slice, consensus partial
    short* hdst = hbuf + (((t + 1) & 1) * 32 + g) * (16 * DM);
    float ps = 0.0f;
#pragma unroll
    for (int r = 0; r < 4; ++r) {
      float gg = fsig(accg[r] + xg);
      float cc = ftanh(accu[r] + xu);
      float h = gg * cc + (1.0f - gg) * hm[r];
      hm[r] = h;
      ps += h;
      hdst[(lq * 4 + r) * DM + col] = f2bf(h);
    }
    ps += __shfl_xor(ps, 16);
    ps += __shfl_xor(ps, 32);
    if (l < 16) part[((bat * 4 + nb) * SEQ + t) * DM + col] = ps;
    if (l == 0)
      __hip_atomic_store(flags + fbase + s * 4 + w, t + 1, __ATOMIC_RELEASE,
                         __HIP_MEMORY_SCOPE_AGENT);
  }
}

// ---- consensus = sum(partials)/64 -> LayerNorm -> bf16 A-fragments ----
__global__ __launch_bounds__(1024) void k_ln(const float* __restrict__ part,
                                             const float* __restrict__ lnw,
                                             const float* __restrict__ lnb,
                                             short* __restrict__ nfrag) {
  __shared__ short tile[16 * DM];           // 16 KB
  int tid = threadIdx.x, w = tid >> 6, l = tid & 63;
  int bI = blockIdx.x;                      // 0..127  (16 rows each)
  int m = bI * 16 + w;
  int bat = m >> 8, t = m & 255;
  const float* p0 = part + ((bat * 4) * SEQ + t) * DM;
  float vx[8];
#pragma unroll
  for (int j = 0; j < 8; ++j) {
    int d = l * 8 + j;
    vx[j] = (p0[d] + p0[d + 131072] + p0[d + 262144] + p0[d + 393216]) * (1.0f / 64.0f);
  }
  float s = 0;
#pragma unroll
  for (int j = 0; j < 8; ++j) s += vx[j];
  for (int msk = 1; msk < 64; msk <<= 1) s += __shfl_xor(s, msk);
  float mean = s * (1.0f / 512.0f);
  float q = 0;
#pragma unroll
  for (int j = 0; j < 8; ++j) { float d = vx[j] - mean; q += d * d; }
  for (int msk = 1; msk < 64; msk <<= 1) q += __shfl_xor(q, msk);
  float rs = rsqrtf(q * (1.0f / 512.0f) + 1e-5f);
#pragma unroll
  for (int j = 0; j < 8; ++j) {
    int d = l * 8 + j;
    tile[w * DM + d] = f2bf((vx[j] - mean) * rs * lnw[d] + lnb[d]);
  }
  __syncthreads();
  // re-emit in A-fragment order: thread tid -> (kt = w, lane l)
  s8v val = *(const s8v*)(&tile[(l & 15) * DM + w * 32 + ((l >> 4) << 3)]);
  *(s8v*)(nfrag + ((bI * KT + w) * 64 + l) * 8) = val;
}

// ---- logits = normed @ Wh + bh : [2048][32000] f32 out ----
__global__ __launch_bounds__(512) void k_logits(const short* __restrict__ nfrag,
                                                const short* __restrict__ whpk,
                                                const float* __restrict__ bh,
                                                float* __restrict__ out) {
  int tid = threadIdx.x, l = tid & 63, w = tid >> 6;  // 8 waves
  int wm = w >> 2, wn = w & 3;
  int ntb = blockIdx.x;   // 0..124 (256 cols each)
  int mtb = blockIdx.y;   // 0..7   (256 rows each)
  f4v acc[8][4];
#pragma unroll
  for (int mi = 0; mi < 8; ++mi)
#pragma unroll
    for (int ni = 0; ni < 4; ++ni) acc[mi][ni] = 0;
  for (int kt = 0; kt < KT; ++kt) {
    s8v bf[4];
#pragma unroll
    for (int ni = 0; ni < 4; ++ni)
      bf[ni] = *(const s8v*)(whpk + (((ntb * 16 + wn * 4 + ni) * KT + kt) * 64 + l) * 8);
#pragma unroll
    for (int mi = 0; mi < 8; ++mi) {
      s8v a = *(const s8v*)(nfrag + (((mtb * 16 + wm * 8 + mi) * KT + kt) * 64 + l) * 8);
#pragma unroll
      for (int ni = 0; ni < 4; ++ni)
        acc[mi][ni] = __builtin_amdgcn_mfma_f32_16x16x32_bf16(a, bf[ni], acc[mi][ni], 0, 0, 0);
    }
  }
#pragma unroll
  for (int ni = 0; ni < 4; ++ni) {
    int n = (ntb * 16 + wn * 4 + ni) * 16 + (l & 15);
    float bias = bh[n];
#pragma unroll
    for (int mi = 0; mi < 8; ++mi) {
      int mrow = (mtb * 16 + wm * 8 + mi) * 16 + ((l >> 4) << 2);
#pragma unroll
      for (int r = 0; r < 4; ++r)
        out[(long)(mrow + r) * VOCAB + n] = acc[mi][ni][r] + bias;
    }
  }
}

extern "C" void kernel_launch(void* const* d_in, const int* in_sizes, int n_in,
                              void* d_out, int out_size, void* d_ws, size_t ws_size,
                              hipStream_t stream) {
  (void)in_sizes; (void)n_in; (void)out_size; (void)ws_size;
  const int*   idx = (const int*)  d_in[0];
  const float* emb = (const float*)d_in[1];
  const float* mn  = (const float*)d_in[2];
  const float* Wg  = (const float*)d_in[3];
  const float* bg  = (const float*)d_in[4];
  const float* Wu  = (const float*)d_in[5];
  const float* bu  = (const float*)d_in[6];
  const float* lnw = (const float*)d_in[7];
  const float* lnb = (const float*)d_in[8];
  const float* Wh  = (const float*)d_in[9];
  const float* bh  = (const float*)d_in[10];
  float* out = (float*)d_out;
  char* ws = (char*)d_ws;
  short* xfrag  = (short*)(ws + OFF_XFRAG);
  short* hbuf   = (short*)(ws + OFF_HBUF);   // reuses xfrag region (dead by then)
  short* bpktop = (short*)(ws + OFF_BPKTOP);
  short* bpkrec = (short*)(ws + OFF_BPKREC);
  short* whpk   = (short*)(ws + OFF_WHPK);
  float* xgu    = (float*)(ws + OFF_XGU);
  float* part   = (float*)(ws + OFF_PART);
  short* nfrag  = (short*)(ws + OFF_NORM);
  int*   flags  = (int*)  (ws + OFF_FLAGS);  // 0xAA poison = negative = not-ready

  k_packw <<<dim3(512),      dim3(256),  0, stream>>>(Wg, Wu, bpktop, bpkrec);
  k_packwh<<<dim3(8000),     dim3(256),  0, stream>>>(Wh, whpk);
  k_gather<<<dim3(512),      dim3(256),  0, stream>>>(idx, emb, xfrag);
  k_xgemm <<<dim3(32, 16),   dim3(256),  0, stream>>>(xfrag, bpktop, bg, bu, xgu);
  k_recur <<<dim3(256),      dim3(256),  0, stream>>>(bpkrec, xgu, mn, part, hbuf, flags);
  k_ln    <<<dim3(128),      dim3(1024), 0, stream>>>(part, lnw, lnb, nfrag);
  k_logits<<<dim3(125, 8),   dim3(512),  0, stream>>>(nfrag, whpk, bh, out);
}